// Round 4
// baseline (526.564 us; speedup 1.0000x reference)
//
#include <hip/hip_runtime.h>

// ---------------------------------------------------------------------------
// AttentionPooling: out[b,o] = sum_p softmax_over_o(qk^T)[o,p] * vbar[b,p]
//   q = wq x + bq, k = wk x + bk   (GEMM M=64 K=512 N=4096 per batch)
//   vbar[p] = mean_n (wv x)[p,n] + bv  -> 4th MFMA accumulator, single-pass
//             bf16 (error averages over N=4096; R3 absmax 4.9e-4 vs 1.8e-3).
// q/k use 3-pass bf16 hi/lo emulation (wh*xh + wl*xh + wh*xl).
// R4: 2 launches total. setup = zero(logits/vsum/counters) + w->bf16 prep.
//     proj = projections + per-tile logits + last-block-per-batch softmax
//     epilogue (device counter; agent-scope atomic loads for coherence).
//     Pipeline holds converted bf16 hi/lo frags (16 regs) not fp32 (32 regs).
// ---------------------------------------------------------------------------

typedef __attribute__((ext_vector_type(8))) short short8;          // 8 bf16
typedef __attribute__((ext_vector_type(4))) float floatx4;

#define MFMA16(a, b, c) __builtin_amdgcn_mfma_f32_16x16x32_bf16((a), (b), (c), 0, 0, 0)

__device__ __forceinline__ unsigned short f2bf(float f) {
  unsigned int u = __float_as_uint(f);
  u = u + 0x7fffu + ((u >> 16) & 1u);   // RNE
  return (unsigned short)(u >> 16);
}
__device__ __forceinline__ float bf2f(unsigned short h) {
  return __uint_as_float(((unsigned int)h) << 16);
}

constexpr int CB = 32;        // batch
constexpr int CC = 512;       // channels
constexpr int CO = 64;        // C/8
constexpr int NN = 4096;      // H*W
constexpr int QROW = 72;      // logits-exchange row stride (64 + 8 pad), ushorts

// ws layout: logits fp32[32*64*64] | vsum fp32[32*64] | cnt int[32] |
//            ws5 bf16[5][16][64][32]  (0=wq_hi 1=wq_lo 2=wk_hi 3=wk_lo 4=wv_hi)
constexpr int ZERO_TOT = CB * CO * CO + CB * CO + CB;   // 133152 words
constexpr int WMAT = 16 * 64 * 32;                      // 32768 ushorts/matrix

__global__ __launch_bounds__(256) void setup_kernel(
    const float* __restrict__ wq, const float* __restrict__ wk,
    const float* __restrict__ wv, float* __restrict__ zbase,
    unsigned short* __restrict__ ws5)
{
  const int blk = blockIdx.x;
  const int t = threadIdx.x;
  if (blk < 64) {            // ---- w -> bf16 hi/lo prep ----
    const int gid = blk * 256 + t;                 // 0..16383
#pragma unroll
    for (int e = 0; e < 2; ++e) {
      const int idx = e * 16384 + gid;             // 0..32767
      const int o = idx >> 9, c = idx & 511;
      const int dst = ((c >> 5) * 64 + o) * 32 + (c & 31);
      const float q = wq[idx], k = wk[idx], v = wv[idx];
      const unsigned short qh = f2bf(q), kh = f2bf(k);
      ws5[dst]            = qh;
      ws5[dst + WMAT]     = f2bf(q - bf2f(qh));
      ws5[dst + 2 * WMAT] = kh;
      ws5[dst + 3 * WMAT] = f2bf(k - bf2f(kh));
      ws5[dst + 4 * WMAT] = f2bf(v);
    }
  } else {                   // ---- zero logits + vsum + counters ----
    for (int i = (blk - 64) * 256 + t; i < ZERO_TOT; i += 64 * 256)
      zbase[i] = 0.0f;
  }
}

__global__ __launch_bounds__(256, 2) void proj_kernel(
    const float* __restrict__ x, const unsigned short* __restrict__ ws5,
    const float* __restrict__ bq, const float* __restrict__ bk,
    const float* __restrict__ bv, float* __restrict__ logits,
    float* __restrict__ vsum, int* __restrict__ cnt, float* __restrict__ out)
{
  __shared__ __align__(16) unsigned short smem[4 * 64 * QROW];  // 36 KiB
  __shared__ float vps[4][64];
  __shared__ int is_last;

  const int t    = threadIdx.x;
  const int lane = t & 63;
  const int wave = t >> 6;
  const int quad = lane >> 4;
  const int l15  = lane & 15;
  const int b    = blockIdx.x >> 5;
  const int tile = blockIdx.x & 31;

  floatx4 accq[4][2], acck[4][2], accv[4][2];
#pragma unroll
  for (int mf = 0; mf < 4; ++mf)
#pragma unroll
    for (int nf = 0; nf < 2; ++nf) {
      accq[mf][nf] = (floatx4)0.0f;
      acck[mf][nf] = (floatx4)0.0f;
      accv[mf][nf] = (floatx4)0.0f;
    }

  // per-lane x pointer: row c = chunk*32 + quad*8 + j, col n = tile*128 +
  // wave*32 + nf*16 + l15
  const float* xp = x + (size_t)b * CC * NN + (size_t)(quad * 8) * NN
                      + tile * 128 + wave * 32 + l15;

  float xv[2][8];
  auto load_x = [&](const float* p) {
#pragma unroll
    for (int j = 0; j < 8; ++j) {
      xv[0][j] = p[(size_t)j * NN];
      xv[1][j] = p[(size_t)j * NN + 16];
    }
  };
  auto cvt = [&](short8 xh[2], short8 xl[2]) {
#pragma unroll
    for (int nf = 0; nf < 2; ++nf)
#pragma unroll
      for (int j = 0; j < 8; ++j) {
        const unsigned short h = f2bf(xv[nf][j]);
        xh[nf][j] = (short)h;
        xl[nf][j] = (short)f2bf(xv[nf][j] - bf2f(h));
      }
  };
  auto compute = [&](const short8 xh[2], const short8 xl[2], int ch) {
    const unsigned short* wch = ws5 + ch * 2048 + l15 * 32 + quad * 8;
#pragma unroll
    for (int mf = 0; mf < 4; ++mf) {
      const unsigned short* wo = wch + mf * 512;
      const short8 aqh = *reinterpret_cast<const short8*>(wo);
      const short8 aql = *reinterpret_cast<const short8*>(wo + WMAT);
      const short8 akh = *reinterpret_cast<const short8*>(wo + 2 * WMAT);
      const short8 akl = *reinterpret_cast<const short8*>(wo + 3 * WMAT);
      const short8 avh = *reinterpret_cast<const short8*>(wo + 4 * WMAT);
#pragma unroll
      for (int nf = 0; nf < 2; ++nf) {
        accq[mf][nf] = MFMA16(aqh, xh[nf], accq[mf][nf]);
        accq[mf][nf] = MFMA16(aql, xh[nf], accq[mf][nf]);
        accq[mf][nf] = MFMA16(aqh, xl[nf], accq[mf][nf]);
        acck[mf][nf] = MFMA16(akh, xh[nf], acck[mf][nf]);
        acck[mf][nf] = MFMA16(akl, xh[nf], acck[mf][nf]);
        acck[mf][nf] = MFMA16(akh, xl[nf], acck[mf][nf]);
        accv[mf][nf] = MFMA16(avh, xh[nf], accv[mf][nf]);
      }
    }
  };

  // software pipeline: loads(k+1) in flight during compute(k); converted
  // bf16 hi/lo double-buffered (16 regs/chunk vs 32 fp32).
  short8 xh0[2], xl0[2], xh1[2], xl1[2];
  load_x(xp); xp += (size_t)32 * NN;
  cvt(xh0, xl0);
  for (int ch = 0; ch < 14; ch += 2) {
    load_x(xp); xp += (size_t)32 * NN;
    compute(xh0, xl0, ch);
    cvt(xh1, xl1);
    load_x(xp); xp += (size_t)32 * NN;
    compute(xh1, xl1, ch + 1);
    cvt(xh0, xl0);
  }
  load_x(xp);
  compute(xh0, xl0, 14);
  cvt(xh1, xl1);
  compute(xh1, xl1, 15);

  // ---- biases (C/D layout: row o = mf*16 + quad*4 + r, col n = l15) ----
#pragma unroll
  for (int mf = 0; mf < 4; ++mf)
#pragma unroll
    for (int r = 0; r < 4; ++r) {
      const int o = mf * 16 + quad * 4 + r;
      const float bqv = bq[o], bkv = bk[o];
#pragma unroll
      for (int nf = 0; nf < 2; ++nf) {
        accq[mf][nf][r] += bqv;
        acck[mf][nf][r] += bkv;
      }
    }

  // ---- logits partial: S = q k^T over this n-tile (hi/lo 3-pass via LDS) ----
  constexpr int QHI = 0, QLO = 4608, KHI = 9216, KLO = 13824;
  floatx4 accS[4];
#pragma unroll
  for (int mf = 0; mf < 4; ++mf) accS[mf] = (floatx4)0.0f;

  for (int hh = 0; hh < 2; ++hh) {
    __syncthreads();
    if ((wave >> 1) == hh) {
      const int nbase = (wave & 1) * 32;
#pragma unroll
      for (int mf = 0; mf < 4; ++mf)
#pragma unroll
        for (int nf = 0; nf < 2; ++nf)
#pragma unroll
          for (int r = 0; r < 4; ++r) {
            const int o  = mf * 16 + quad * 4 + r;
            const int nc = nbase + nf * 16 + l15;
            const float qv = accq[mf][nf][r];
            const float kv = acck[mf][nf][r];
            const unsigned short qh = f2bf(qv);
            const unsigned short kh = f2bf(kv);
            smem[QHI + o * QROW + nc] = qh;
            smem[QLO + o * QROW + nc] = f2bf(qv - bf2f(qh));
            smem[KHI + o * QROW + nc] = kh;
            smem[KLO + o * QROW + nc] = f2bf(kv - bf2f(kh));
          }
    }
    __syncthreads();
#pragma unroll
    for (int ks = 0; ks < 2; ++ks) {
      const short8 bh = *reinterpret_cast<const short8*>(
          &smem[KHI + (wave * 16 + l15) * QROW + ks * 32 + quad * 8]);
      const short8 bl = *reinterpret_cast<const short8*>(
          &smem[KLO + (wave * 16 + l15) * QROW + ks * 32 + quad * 8]);
#pragma unroll
      for (int mf = 0; mf < 4; ++mf) {
        const short8 ah = *reinterpret_cast<const short8*>(
            &smem[QHI + (mf * 16 + l15) * QROW + ks * 32 + quad * 8]);
        const short8 al = *reinterpret_cast<const short8*>(
            &smem[QLO + (mf * 16 + l15) * QROW + ks * 32 + quad * 8]);
        accS[mf] = MFMA16(ah, bh, accS[mf]);
        accS[mf] = MFMA16(al, bh, accS[mf]);
        accS[mf] = MFMA16(ah, bl, accS[mf]);
      }
    }
  }

#pragma unroll
  for (int mf = 0; mf < 4; ++mf)
#pragma unroll
    for (int r = 0; r < 4; ++r) {
      const int o = mf * 16 + quad * 4 + r;
      const int p = wave * 16 + l15;
      atomicAdd(&logits[((size_t)b * CO + o) * CO + p], accS[mf][r]);
    }

  // ---- v reduction over n: vsum[b,p] += sum over this tile's 128 n ----
#pragma unroll
  for (int mf = 0; mf < 4; ++mf)
#pragma unroll
    for (int r = 0; r < 4; ++r) {
      float sv = accv[mf][0][r] + accv[mf][1][r];
      sv += __shfl_xor(sv, 1); sv += __shfl_xor(sv, 2);
      sv += __shfl_xor(sv, 4); sv += __shfl_xor(sv, 8);
      if (l15 == 0) vps[wave][mf * 16 + quad * 4 + r] = sv;
    }
  __syncthreads();
  if (t < CO) {
    const float s = vps[0][t] + vps[1][t] + vps[2][t] + vps[3][t];
    atomicAdd(&vsum[b * CO + t], s);
  }

  // ---- last block for this batch runs the softmax epilogue ----
  __syncthreads();   // all atomics above issued & drained (barrier waits vmcnt)
  if (t == 0) {
    __threadfence();
    const int old = __hip_atomic_fetch_add(&cnt[b], 1, __ATOMIC_ACQ_REL,
                                           __HIP_MEMORY_SCOPE_AGENT);
    is_last = (old == CB - 1) ? 1 : 0;
  }
  __syncthreads();
  if (!is_last) return;

  float* ls = reinterpret_cast<float*>(smem);   // [64][65] fp32, 16.6 KiB
#pragma unroll
  for (int i = 0; i < 16; ++i) {
    const int idx = t + i * 256;                // 0..4095
    const float v = __hip_atomic_load(&logits[(size_t)b * CO * CO + idx],
                                      __ATOMIC_RELAXED, __HIP_MEMORY_SCOPE_AGENT);
    ls[(idx >> 6) * 65 + (idx & 63)] = v;
  }
  __syncthreads();

  __shared__ float w2_s[CO], cmax_s[CO];
  if (t < CO) {  // column stats for p=t: softmax over rows o
    float m = -1e30f;
    for (int o = 0; o < CO; ++o) m = fmaxf(m, ls[o * 65 + t]);
    float sum = 0.f;
    for (int o = 0; o < CO; ++o) sum += __expf(ls[o * 65 + t] - m);
    cmax_s[t] = m;
    const float vs = __hip_atomic_load(&vsum[b * CO + t], __ATOMIC_RELAXED,
                                       __HIP_MEMORY_SCOPE_AGENT);
    w2_s[t] = (vs * (1.0f / 4096.0f) + bv[t]) / sum;
  }
  __syncthreads();

  if (t < CO) {
    float acc = 0.f;
    for (int p = 0; p < CO; ++p)
      acc += __expf(ls[t * 65 + p] - cmax_s[p]) * w2_s[p];
    out[b * CO + t] = acc;
  }
}

extern "C" void kernel_launch(void* const* d_in, const int* in_sizes, int n_in,
                              void* d_out, int out_size, void* d_ws, size_t ws_size,
                              hipStream_t stream) {
  const float* x  = (const float*)d_in[0];
  const float* wq = (const float*)d_in[1];
  const float* bq = (const float*)d_in[2];
  const float* wk = (const float*)d_in[3];
  const float* bk = (const float*)d_in[4];
  const float* wv = (const float*)d_in[5];
  const float* bv = (const float*)d_in[6];
  float* out = (float*)d_out;

  float* logits = (float*)d_ws;                        // 131072 floats
  float* vsum   = logits + CB * CO * CO;               // 2048 floats
  int*   cnt    = (int*)(vsum + CB * CO);              // 32 ints
  unsigned short* ws5 = (unsigned short*)(cnt + CB);   // 5*32768 ushorts

  setup_kernel<<<128, 256, 0, stream>>>(wq, wk, wv, logits, ws5);
  proj_kernel<<<CB * 32, 256, 0, stream>>>(x, ws5, bq, bk, bv, logits, vsum,
                                           cnt, out);
}